// Round 1
// baseline (394.861 us; speedup 1.0000x reference)
//
#include <hip/hip_runtime.h>
#include <hip/hip_bf16.h>
#include <math.h>

#define N_IN   512
#define N_OUT  256
#define KDEG   3
#define GRIDSZ 254            // N_OUT - K + 1
#define NCOEF  (GRIDSZ + KDEG) // 257
#define BATCH  1024
#define LN_EPS 1e-5f

// tiling
#define OT 32                 // o tile per block
#define IC 32                 // i chunk per block
#define BT 256                // b tile per block (= blockDim)
#define OBLK (N_OUT / OT)     // 8
#define IBLK (N_IN / IC)      // 16
#define BBLK (BATCH / BT)     // 4

// grid constants: step = 2/254, g0 = -1 - 3*step, u = (x-g0)*127 in [0,260)
#define STEPF   (2.0f / 254.0f)
#define G0F     (-1.0f - 3.0f * STEPF)
#define INVSTEP 127.0f

__global__ __launch_bounds__(256) void kan_partial_kernel(
    const float* __restrict__ x, const float* __restrict__ W,
    const float* __restrict__ sw, float* __restrict__ part)
{
    const int ob = blockIdx.x % OBLK;
    const int ib = blockIdx.x / OBLK;
    const int bb = blockIdx.y;
    const int o0 = ob * OT, i0 = ib * IC, b0 = bb * BT;
    const int tid = threadIdx.x;

    __shared__ float xs[IC][BT + 1];  // +1 pad: conflict-free staging writes
    __shared__ float Ws[OT][IC];

    // stage x tile (coalesced over i)
    for (int e = tid; e < IC * BT; e += 256) {
        int bl = e / IC, ii = e % IC;
        xs[ii][bl] = x[(size_t)(b0 + bl) * N_IN + i0 + ii];
    }
    // stage W tile
    for (int e = tid; e < OT * IC; e += 256) {
        int oo = e / IC, ii = e % IC;
        Ws[oo][ii] = W[(size_t)(o0 + oo) * N_IN + i0 + ii];
    }
    __syncthreads();

    float acc[OT];
#pragma unroll
    for (int oo = 0; oo < OT; ++oo) acc[oo] = 0.f;

    const int b = b0 + tid;   // lane <-> batch row

    for (int ii = 0; ii < IC; ++ii) {
        const float xv = xs[ii][tid];
        const float tx = tanhf(xv);

        // cubic B-spline local basis
        const float u = (xv - G0F) * INVSTEP;
        const bool has = (u >= 0.f) && (u < 260.f);
        float uf = has ? u : 0.f;
        int idx = (int)uf;              // floor, in [0,259]
        if (idx > 259) idx = 259;
        const float t  = uf - (float)idx;
        const float t2 = t * t, t3 = t2 * t;
        const float omt = 1.f - t;
        float w0 = (omt * omt * omt) * (1.f / 6.f);
        float w1 = (3.f * t3 - 6.f * t2 + 4.f) * (1.f / 6.f);
        float w2 = (-3.f * t3 + 3.f * t2 + 3.f * t + 1.f) * (1.f / 6.f);
        float w3 = t3 * (1.f / 6.f);
        if (!has) { w0 = w1 = w2 = w3 = 0.f; }

        // clip to valid coefficient range [0,256] (reference array bounds)
        const int pb = idx - 3;
        int p0 = pb;     if (p0 < 0 || p0 > 256) { w0 = 0.f; p0 = 0; }
        int p1 = pb + 1; if (p1 < 0 || p1 > 256) { w1 = 0.f; p1 = 0; }
        int p2 = pb + 2; if (p2 < 0 || p2 > 256) { w2 = 0.f; p2 = 0; }
        int p3 = pb + 3; if (p3 < 0 || p3 > 256) { w3 = 0.f; p3 = 0; }

        const float* base = sw + ((size_t)o0 * N_IN + (i0 + ii)) * NCOEF;
#pragma unroll 8
        for (int oo = 0; oo < OT; ++oo) {
            const float* p = base + (size_t)oo * ((size_t)N_IN * NCOEF);
            acc[oo] += tx * Ws[oo][ii]
                     + w0 * p[p0] + w1 * p[p1] + w2 * p[p2] + w3 * p[p3];
        }
    }

    // write partial slab: part[ib][b][o0+oo]
    float* dst = part + ((size_t)ib * BATCH + b) * N_OUT + o0;
#pragma unroll
    for (int oo = 0; oo < OT; ++oo) dst[oo] = acc[oo];
}

__global__ __launch_bounds__(256) void kan_ln_kernel(
    const float* __restrict__ part, const float* __restrict__ prelu_a,
    float* __restrict__ out)
{
    const int b = blockIdx.x;
    const int t = threadIdx.x;      // t <-> output column o

    float s = 0.f;
#pragma unroll
    for (int k = 0; k < IBLK; ++k)
        s += part[((size_t)k * BATCH + b) * N_OUT + t];

    // block reduction: mean and mean-of-squares over 256 values
    float v1 = s, v2 = s * s;
#pragma unroll
    for (int d = 1; d < 64; d <<= 1) {
        v1 += __shfl_xor(v1, d);
        v2 += __shfl_xor(v2, d);
    }
    __shared__ float red1[4], red2[4];
    const int wave = t >> 6;
    if ((t & 63) == 0) { red1[wave] = v1; red2[wave] = v2; }
    __syncthreads();
    const float tot1 = red1[0] + red1[1] + red1[2] + red1[3];
    const float tot2 = red2[0] + red2[1] + red2[2] + red2[3];

    const float mu  = tot1 * (1.f / N_OUT);
    const float var = tot2 * (1.f / N_OUT) - mu * mu;
    const float inv = rsqrtf(var + LN_EPS);
    const float yn  = (s - mu) * inv;
    const float a   = prelu_a[0];
    out[(size_t)b * N_OUT + t] = (yn >= 0.f) ? yn : a * yn;
}

extern "C" void kernel_launch(void* const* d_in, const int* in_sizes, int n_in,
                              void* d_out, int out_size, void* d_ws, size_t ws_size,
                              hipStream_t stream)
{
    const float* x  = (const float*)d_in[0];
    const float* W  = (const float*)d_in[1];
    const float* sw = (const float*)d_in[2];
    const float* pa = (const float*)d_in[3];
    float* out  = (float*)d_out;
    float* part = (float*)d_ws;   // IBLK * BATCH * N_OUT floats = 16 MB

    dim3 grid1(OBLK * IBLK, BBLK);
    kan_partial_kernel<<<grid1, 256, 0, stream>>>(x, W, sw, part);

    kan_ln_kernel<<<BATCH, 256, 0, stream>>>(part, pa, out);
}

// Round 2
// 111.489 us; speedup vs baseline: 3.5417x; 3.5417x over previous
//
#include <hip/hip_runtime.h>
#include <math.h>

#define N_IN   512
#define N_OUT  256
#define NCOEF  257
#define BATCH  1024
#define LN_EPS 1e-5f

#define OC 16        // o per block
#define IG 32        // i per block
#define BC 512       // b per block

#define STEPF (2.0f/254.0f)
#define G0F   (-1.0f - 3.0f*STEPF)

// slab layout: element (c, oo) at slab[c*16 + (oo ^ (((c>>4)&3)<<2))]
// -> read of rows p..p, cols og*4..og*4+3 is one aligned ds_read_b128,
//    row-dependent XOR spreads random rows p across banks.

__global__ __launch_bounds__(256, 2) void kan_main(
    const float* __restrict__ x, const float* __restrict__ W,
    const float* __restrict__ sw, float* __restrict__ part)
{
    const int bid = blockIdx.x;
    const int oc = bid & 15;
    const int ig = (bid >> 4) & 15;
    const int bc = bid >> 8;
    const int o0 = oc * OC;
    const int i0 = ig * IG;
    const int b0 = bc * BC;
    const int t  = threadIdx.x;

    __shared__ __align__(16) float slab[NCOEF * 16];  // 16.4 KB
    __shared__ float4 wls[BC];                        // w0..w3 per local b
    __shared__ float2 txpb[BC];                       // (tanh(x), float(pb))
    __shared__ __align__(16) float Wl[OC];

    // compute-pass mapping: lane = (bl:16, og:4); thread covers o = o0+og*4+j
    const int wv  = t >> 6;
    const int bl  = (t >> 2) & 15;
    const int og  = t & 3;
    const int lbb = wv * 128;       // wave owns 128 local b: 8 passes x 16

    // staging mapping: thread covers row soo, c = e*64 + scb*4 + j
    const int soo  = t >> 4;
    const int scb  = t & 15;
    const int colp = soo ^ (((scb >> 2) & 3) << 2);   // (c>>4)&3 == (scb>>2)&3

    float4 acc[8];
#pragma unroll
    for (int bp = 0; bp < 8; ++bp) acc[bp] = make_float4(0.f, 0.f, 0.f, 0.f);

    for (int ii = 0; ii < IG; ++ii) {
        const int i = i0 + ii;
        __syncthreads();   // previous iteration's readers done

        // ---- per-(b,i) weights: closed-form cubic B-spline + tanh, 2 b per thread
#pragma unroll
        for (int r = 0; r < 2; ++r) {
            const int lb = t + r * 256;
            const float xv = x[(size_t)(b0 + lb) * N_IN + i];
            const float e2 = __expf(2.f * xv);
            const float tx = 1.f - 2.f / (e2 + 1.f);    // tanh(xv)
            const float u  = (xv - G0F) * 127.f;
            const bool has = (u >= 0.f) && (u < 260.f);
            const float uf = has ? u : 0.f;
            int m = (int)uf;
            if (m > 259) m = 259;
            const float tt = uf - (float)m;
            const float t2 = tt * tt, t3 = t2 * tt;
            const float omt = 1.f - tt;
            float a0 = omt * omt * omt * (1.f / 6.f);
            float a1 = (3.f * t3 - 6.f * t2 + 4.f) * (1.f / 6.f);
            float a2 = (-3.f * t3 + 3.f * t2 + 3.f * tt + 1.f) * (1.f / 6.f);
            float a3 = t3 * (1.f / 6.f);
            if (!has) { a0 = a1 = a2 = a3 = 0.f; }
            const int pb = m - 3;
            const int pbc = pb < 0 ? 0 : (pb > 253 ? 253 : pb);
            const int d = pbc - pb;   // in [-3,3]: wslot[k] = a[k+d], OOR -> 0
            if (d >= 1)  { a0 = a1; a1 = a2; a2 = a3; a3 = 0.f; }
            if (d >= 2)  { a0 = a1; a1 = a2; a2 = a3; a3 = 0.f; }
            if (d >= 3)  { a0 = a1; a1 = a2; a2 = a3; a3 = 0.f; }
            if (d <= -1) { a3 = a2; a2 = a1; a1 = a0; a0 = 0.f; }
            if (d <= -2) { a3 = a2; a2 = a1; a1 = a0; a0 = 0.f; }
            if (d <= -3) { a3 = a2; a2 = a1; a1 = a0; a0 = 0.f; }
            wls[lb]  = make_float4(a0, a1, a2, a3);
            txpb[lb] = make_float2(tx, (float)pbc);
        }

        if (t < OC) Wl[t] = W[(size_t)(o0 + t) * N_IN + i];

        // ---- stage sw slab: 16 o-rows x 257 coeffs, swizzled
        {
            const float* rp = sw + ((size_t)(o0 + soo) * N_IN + i) * NCOEF;
#pragma unroll
            for (int e = 0; e < 4; ++e) {
                const int c0 = e * 64 + scb * 4;   // 16 lanes -> 256 B contiguous
                const float v0 = rp[c0 + 0], v1 = rp[c0 + 1];
                const float v2 = rp[c0 + 2], v3 = rp[c0 + 3];
                float* wp = &slab[(c0 << 4) + colp];
                wp[0]  = v0;
                wp[16] = v1;
                wp[32] = v2;
                wp[48] = v3;
            }
            if (scb == 15) slab[(256 << 4) + soo] = rp[256];  // tail, swz(256)=0
        }
        __syncthreads();

        const float4 Wv = *reinterpret_cast<const float4*>(&Wl[og << 2]);

#pragma unroll
        for (int bp = 0; bp < 8; ++bp) {
            const int lb = lbb + bp * 16 + bl;
            const float4 w4 = wls[lb];      // broadcast across 4 og lanes
            const float2 tp = txpb[lb];
            const int pb = (int)tp.y;
            float4 a = acc[bp];
            a.x += tp.x * Wv.x; a.y += tp.x * Wv.y;
            a.z += tp.x * Wv.z; a.w += tp.x * Wv.w;
#pragma unroll
            for (int k = 0; k < 4; ++k) {
                const int p = pb + k;
                const int cidx = (p << 4) + ((og ^ ((p >> 4) & 3)) << 2);
                const float4 s4 = *reinterpret_cast<const float4*>(&slab[cidx]);
                const float wk = (k == 0) ? w4.x : (k == 1) ? w4.y
                               : (k == 2) ? w4.z : w4.w;
                a.x += wk * s4.x; a.y += wk * s4.y;
                a.z += wk * s4.z; a.w += wk * s4.w;
            }
            acc[bp] = a;
        }
    }

    // ---- write partial slab [ig][b][o]
    float* dst = part + ((size_t)ig * BATCH + b0) * N_OUT + o0 + (og << 2);
#pragma unroll
    for (int bp = 0; bp < 8; ++bp) {
        const int lb = lbb + bp * 16 + bl;
        *reinterpret_cast<float4*>(&dst[(size_t)lb * N_OUT]) = acc[bp];
    }
}

__global__ __launch_bounds__(256) void kan_ln(
    const float* __restrict__ part, const float* __restrict__ prelu_a,
    float* __restrict__ out)
{
    const int b = blockIdx.x;
    const int t = threadIdx.x;      // t <-> output column o

    float s = 0.f;
#pragma unroll
    for (int k = 0; k < 16; ++k)
        s += part[((size_t)k * BATCH + b) * N_OUT + t];

    float v1 = s, v2 = s * s;
#pragma unroll
    for (int d = 1; d < 64; d <<= 1) {
        v1 += __shfl_xor(v1, d);
        v2 += __shfl_xor(v2, d);
    }
    __shared__ float r1[4], r2[4];
    if ((t & 63) == 0) { r1[t >> 6] = v1; r2[t >> 6] = v2; }
    __syncthreads();
    const float tot1 = r1[0] + r1[1] + r1[2] + r1[3];
    const float tot2 = r2[0] + r2[1] + r2[2] + r2[3];

    const float mu  = tot1 * (1.f / N_OUT);
    const float var = tot2 * (1.f / N_OUT) - mu * mu;
    const float inv = rsqrtf(var + LN_EPS);
    const float yn  = (s - mu) * inv;
    const float a   = prelu_a[0];
    out[(size_t)b * N_OUT + t] = (yn >= 0.f) ? yn : a * yn;
}

extern "C" void kernel_launch(void* const* d_in, const int* in_sizes, int n_in,
                              void* d_out, int out_size, void* d_ws, size_t ws_size,
                              hipStream_t stream)
{
    const float* x  = (const float*)d_in[0];
    const float* W  = (const float*)d_in[1];
    const float* sw = (const float*)d_in[2];
    const float* pa = (const float*)d_in[3];
    float* out  = (float*)d_out;
    float* part = (float*)d_ws;   // 16 * 1024 * 256 floats = 16 MB

    kan_main<<<dim3(512), 256, 0, stream>>>(x, W, sw, part);
    kan_ln<<<dim3(1024), 256, 0, stream>>>(part, pa, out);
}